// Round 1
// baseline (730.207 us; speedup 1.0000x reference)
//
#include <hip/hip_runtime.h>
#include <hip/hip_bf16.h>
#include <math.h>

typedef __bf16 bf16;
typedef bf16 bf16x8 __attribute__((ext_vector_type(8)));
typedef float f32x4 __attribute__((ext_vector_type(4)));

// ---- problem constants ----
constexpr int BATCH = 64;
constexpr int CIN   = 2048;
constexpr int HIDN  = 2048;
constexpr int OUTN  = 256;
constexpr int LL    = 196;   // H*W
constexpr int LCAT  = 197;   // pooled + L
constexpr int P1V   = BATCH * LCAT;   // 12608 valid rows
constexpr int P1P   = 12672;          // padded to 99*128
// output offsets (in floats)
constexpr size_t O_ZG   = 0;
constexpr size_t O_OVAL = (size_t)BATCH * OUTN;                   // 16384
constexpr size_t O_ATT  = O_OVAL + (size_t)BATCH * OUTN * 32;     // 540672
constexpr size_t O_ATTR = O_ATT + (size_t)BATCH * OUTN * LL;      // 3751936

// ---- workspace layout (bytes) ----
constexpr size_t WS_XCAT = 0;                            // bf16 [12672][2048] = 51,904,512
constexpr size_t WS_V2   = WS_XCAT;                      // bf16 [2048][2048] (alias; XCAT dead after GEMM1)
constexpr size_t WS_H2T  = WS_XCAT + (size_t)(16u<<20);  // bf16 [2048][2048] (alias, disjoint from V2)
constexpr size_t WS_HT   = 51904512;                     // bf16 [12672][2048]
constexpr size_t WS_Z    = WS_HT + 51904512;             // f32  [256][12672] = 12,976,128
constexpr size_t WS_W1B  = WS_Z + 12976128;              // bf16 8,388,608
constexpr size_t WS_W2B  = WS_W1B + 8388608;             // bf16 1,048,576
constexpr size_t WS_W1OB = WS_W2B + 1048576;             // bf16 8,388,608
constexpr size_t WS_W2OB = WS_W1OB + 8388608;            // bf16 1,048,576
constexpr size_t WS_NRM  = WS_W2OB + 1048576;            // f32 64*196
constexpr size_t WS_SUMS = WS_NRM + 50176;               // f32 [4][2048] (sum1,sumsq1,sum2,sumsq2)
constexpr size_t WS_SC1  = WS_SUMS + 32768;              // f32 2048
constexpr size_t WS_SH1  = WS_SC1 + 8192;
constexpr size_t WS_SC2  = WS_SH1 + 8192;
constexpr size_t WS_SH2  = WS_SC2 + 8192;

// ======================= small utility kernels =======================
__global__ __launch_bounds__(256) void cast_k(const float* __restrict__ s, bf16* __restrict__ d, int n){
  int i = blockIdx.x * 256 + threadIdx.x;
  if (i < n) d[i] = (bf16)s[i];
}
__global__ __launch_bounds__(256) void zero_f32(float* p, int n){
  int i = blockIdx.x * 256 + threadIdx.x;
  if (i < n) p[i] = 0.f;
}
__global__ __launch_bounds__(256) void zero_b16(bf16* p, int n){
  int i = blockIdx.x * 256 + threadIdx.x;
  if (i < n) p[i] = (bf16)0.f;
}

// prep: transpose x (b,c,l) -> Xcat[p=b*197+1+l][c] bf16, plus pooled row at p=b*197
__global__ __launch_bounds__(256) void prep_k(const float* __restrict__ x, bf16* __restrict__ xcat){
  __shared__ float xs[LL][66];
  int b  = blockIdx.x >> 5;
  int cg = blockIdx.x & 31;
  int c0 = cg * 64;
  int t  = threadIdx.x;
  const float* xb = x + (size_t)b * CIN * LL + (size_t)c0 * LL;
  for (int cc = 0; cc < 64; cc++){
    if (t < LL) xs[t][cc] = xb[(size_t)cc * LL + t];
  }
  __syncthreads();
  if (t < 64){
    float s = 0.f;
    for (int l = 0; l < LL; l++) s += xs[l][t];
    xcat[(size_t)(b * LCAT) * CIN + c0 + t] = (bf16)(s * (1.f / (float)LL));
  }
  int lw = t >> 6, cc = t & 63;
  for (int i = 0; i < 49; i++){
    int l = i * 4 + lw;
    xcat[(size_t)(b * LCAT + 1 + l) * CIN + c0 + cc] = (bf16)xs[l][cc];
  }
}

// per-channel (column) sums over rows of a row-major bf16 matrix [rows][2048]
__global__ __launch_bounds__(256) void stats_k(const bf16* __restrict__ src, int rows, int rpg,
                                               float* __restrict__ sum, float* __restrict__ sumsq){
  int o  = blockIdx.x * 256 + threadIdx.x;
  int r0 = blockIdx.y * rpg;
  int r1 = min(rows, r0 + rpg);
  float s = 0.f, q = 0.f;
  for (int r = r0; r < r1; r++){
    float v = (float)src[(size_t)r * 2048 + o];
    s += v; q += v * v;
  }
  atomicAdd(&sum[o], s);
  atomicAdd(&sumsq[o], q);
}

__global__ __launch_bounds__(256) void finalize_k(const float* __restrict__ sum, const float* __restrict__ sumsq,
                                                  const float* __restrict__ g, const float* __restrict__ b,
                                                  float n, float* __restrict__ scale, float* __restrict__ shift){
  int o = blockIdx.x * 256 + threadIdx.x;
  float mu  = sum[o] / n;
  float var = sumsq[o] / n - mu * mu;
  float sc  = g[o] / sqrtf(var + 1e-5f);
  scale[o] = sc;
  shift[o] = b[o] - mu * sc;
}

__global__ __launch_bounds__(256) void zg_k(const float* __restrict__ z, float* __restrict__ dout){
  int gidx = blockIdx.x * 256 + threadIdx.x;   // 16384 = b*256 + c
  int b = gidx >> 8, c = gidx & 255;
  dout[O_ZG + gidx] = z[(size_t)c * P1P + b * LCAT];
}

__global__ __launch_bounds__(256) void nrm_k(const float* __restrict__ z, float* __restrict__ nrm){
  int b = blockIdx.x, t = threadIdx.x;
  if (t >= LL) return;
  float acc = 0.f;
  const float* zb = z + (size_t)b * LCAT + 1 + t;
  for (int c = 0; c < OUTN; c++){
    float v = zb[(size_t)c * P1P];
    acc += v * v;
  }
  nrm[b * LL + t] = sqrtf(acc);
}

__global__ __launch_bounds__(64) void softmax_k(const float* __restrict__ z, const float* __restrict__ nrm,
                                                float* __restrict__ dout){
  int bc = blockIdx.x;         // b*256 + c
  int b  = bc >> 8;
  int lane = threadIdx.x;
  const float* zr = z + (size_t)(bc & 255) * P1P + b * LCAT + 1;
  const float* nr = nrm + b * LL;
  float a[4];
  float mx = -1e30f;
  #pragma unroll
  for (int j = 0; j < 4; j++){
    int l = lane + j * 64;
    if (l < LL){
      float v = zr[l] / fmaxf(nr[l], 1e-12f);   // SCALE == 1.0
      a[j] = v; mx = fmaxf(mx, v);
    } else a[j] = -1e30f;
  }
  #pragma unroll
  for (int s = 1; s < 64; s <<= 1) mx = fmaxf(mx, __shfl_xor(mx, s, 64));
  float sum = 0.f;
  #pragma unroll
  for (int j = 0; j < 4; j++){
    a[j] = (a[j] > -1e29f) ? expf(a[j] - mx) : 0.f;
    sum += a[j];
  }
  #pragma unroll
  for (int s = 1; s < 64; s <<= 1) sum += __shfl_xor(sum, s, 64);
  float inv = 1.f / sum;
  float* o1 = dout + O_ATT  + (size_t)bc * LL;
  float* o2 = dout + O_ATTR + (size_t)bc * LL;
  #pragma unroll
  for (int j = 0; j < 4; j++){
    int l = lane + j * 64;
    if (l < LL){ float r = a[j] * inv; o1[l] = r; o2[l] = r; }
  }
}

// ======================= unified NT MFMA GEMM =======================
// D[i][j] = sum_k P[i][k] * Q[j][k]; both operands K-contiguous rows.
// CFG1: h  = Xcat(12672) x w1b(2048),  K=2048 -> hT bf16
// CFG2: z  = w2b(256)    x bn_relu(hT)(12672), K=2048 -> z f32
// CFG3: h2 = v2(2048)    x w1ob(2048), K=2048 -> h2T bf16
// CFG4: out= w2ob(256)   x bn_relu(h2T)(2048), K=2048 -> d_out remap
// CFG5: v  = attn(32)    x x-rows(256), K=196 (f32 sources) -> v2 bf16
template<int CFG>
__global__ __launch_bounds__(256)
void gemm_k(const void* __restrict__ Ap, const void* __restrict__ Qp, void* __restrict__ Cp,
            const float* __restrict__ sc, const float* __restrict__ sh)
{
  constexpr int BM  = (CFG==1 || CFG==3) ? 128 : (CFG==5 ? 32 : 64);
  constexpr int BN  = (CFG==5) ? 256 : 128;
  constexpr int WR  = (CFG==1 || CFG==3) ? 2 : 1;
  constexpr int WC  = 4 / WR;
  constexpr int WTM = BM / WR, WTN = BN / WC;
  constexpr int FM  = WTM / 16, FN = WTN / 16;
  constexpr int KT  = (CFG==5) ? 4 : 32;
  constexpr bool KB   = (CFG==5);
  constexpr bool F32S = (CFG==5);
  constexpr bool QBN  = (CFG==2) || (CFG==4);
  constexpr int LDA = (CFG==5) ? LL : 2048;
  constexpr int LDQ = (CFG==5) ? LL : 2048;
  constexpr int CA  = BM / 32;
  constexpr int CQ  = BN / 32;

  __shared__ bf16 Ps[BM * 64];
  __shared__ bf16 Qs[BN * 64];

  const int t = threadIdx.x;
  const int lane = t & 63;
  const int wid  = t >> 6;
  const int wr = wid / WC, wc = wid % WC;

  size_t aBase = 0, qBase = 0;
  int mOff = 0, nOff = 0;
  if constexpr (CFG == 5){
    int bh = blockIdx.x;                       // b*8 + head
    aBase = (size_t)bh * 32 * LL;
    qBase = ((size_t)(bh >> 3) * 2048 + (size_t)(bh & 7) * 256) * LL;
    mOff = (bh >> 3) * 32;                     // p2 row base (b*32)
    nOff = (bh & 7) * 256;                     // channel base (head*256)
  } else {
    mOff = blockIdx.x * BM;
    nOff = blockIdx.y * BN;
    aBase = (size_t)mOff * LDA;
    qBase = (size_t)nOff * LDQ;
  }

  f32x4 acc[FM][FN] = {};

  for (int kt = 0; kt < KT; ++kt){
    const int k0 = kt * 64;
    bf16x8 ra[CA], rq[CQ];
    #pragma unroll
    for (int i = 0; i < CA; i++){
      int ch = i * 256 + t;
      int row = ch >> 3, kc = ch & 7, kg = k0 + kc * 8;
      if constexpr (F32S){
        const float* g = (const float*)Ap + aBase + (size_t)row * LDA + kg;
        #pragma unroll
        for (int j = 0; j < 8; j++){
          float f = (!KB || (kg + j) < LL) ? g[j] : 0.f;
          ra[i][j] = (bf16)f;
        }
      } else {
        ra[i] = *(const bf16x8*)((const bf16*)Ap + aBase + (size_t)row * LDA + kg);
      }
    }
    #pragma unroll
    for (int i = 0; i < CQ; i++){
      int ch = i * 256 + t;
      int row = ch >> 3, kc = ch & 7, kg = k0 + kc * 8;
      if constexpr (F32S){
        const float* g = (const float*)Qp + qBase + (size_t)row * LDQ + kg;
        #pragma unroll
        for (int j = 0; j < 8; j++){
          float f = ((kg + j) < LL) ? g[j] : 0.f;
          rq[i][j] = (bf16)f;
        }
      } else if constexpr (QBN){
        bf16x8 raw = *(const bf16x8*)((const bf16*)Qp + qBase + (size_t)row * LDQ + kg);
        #pragma unroll
        for (int j = 0; j < 8; j++){
          float f = (float)raw[j] * sc[kg + j] + sh[kg + j];
          rq[i][j] = (bf16)fmaxf(f, 0.f);
        }
      } else {
        rq[i] = *(const bf16x8*)((const bf16*)Qp + qBase + (size_t)row * LDQ + kg);
      }
    }
    __syncthreads();
    #pragma unroll
    for (int i = 0; i < CA; i++){
      int ch = i * 256 + t; int row = ch >> 3, kc = ch & 7;
      *(bf16x8*)&Ps[row * 64 + ((kc ^ (row & 7)) << 3)] = ra[i];
    }
    #pragma unroll
    for (int i = 0; i < CQ; i++){
      int ch = i * 256 + t; int row = ch >> 3, kc = ch & 7;
      *(bf16x8*)&Qs[row * 64 + ((kc ^ (row & 7)) << 3)] = rq[i];
    }
    __syncthreads();
    #pragma unroll
    for (int ks = 0; ks < 2; ++ks){
      const int kcl = ks * 4 + (lane >> 4);
      bf16x8 af[FM], qf[FN];
      #pragma unroll
      for (int m = 0; m < FM; m++){
        int row = wr * WTM + m * 16 + (lane & 15);
        af[m] = *(const bf16x8*)&Ps[row * 64 + ((kcl ^ (row & 7)) << 3)];
      }
      #pragma unroll
      for (int n = 0; n < FN; n++){
        int row = wc * WTN + n * 16 + (lane & 15);
        qf[n] = *(const bf16x8*)&Qs[row * 64 + ((kcl ^ (row & 7)) << 3)];
      }
      #pragma unroll
      for (int m = 0; m < FM; m++)
        #pragma unroll
        for (int n = 0; n < FN; n++)
          acc[m][n] = __builtin_amdgcn_mfma_f32_16x16x32_bf16(af[m], qf[n], acc[m][n], 0, 0, 0);
    }
  }

  // epilogue: C/D map col = lane&15, row = (lane>>4)*4 + r  [verified]
  #pragma unroll
  for (int m = 0; m < FM; m++){
    #pragma unroll
    for (int n = 0; n < FN; n++){
      #pragma unroll
      for (int r = 0; r < 4; r++){
        int row = mOff + wr * WTM + m * 16 + (lane >> 4) * 4 + r;
        int col = nOff + wc * WTN + n * 16 + (lane & 15);
        float v = acc[m][n][r];
        if constexpr (CFG == 1 || CFG == 3 || CFG == 5){
          ((bf16*)Cp)[(size_t)row * 2048 + col] = (bf16)v;
        } else if constexpr (CFG == 2){
          ((float*)Cp)[(size_t)row * P1P + col] = v;
        } else {  // CFG==4: d_out obj_val remap: row=cout, col=p2=b*32+k
          ((float*)Cp)[O_OVAL + (size_t)(col >> 5) * 8192 + (size_t)row * 32 + (col & 31)] = v;
        }
      }
    }
  }
}

// ======================= launch =======================
extern "C" void kernel_launch(void* const* d_in, const int* in_sizes, int n_in,
                              void* d_out, int out_size, void* d_ws, size_t ws_size,
                              hipStream_t stream){
  const float* x   = (const float*)d_in[0];
  const float* w1p = (const float*)d_in[1];
  const float* gp  = (const float*)d_in[2];
  const float* bp  = (const float*)d_in[3];
  const float* w2p = (const float*)d_in[4];
  const float* w1o = (const float*)d_in[5];
  const float* go  = (const float*)d_in[6];
  const float* bo  = (const float*)d_in[7];
  const float* w2o = (const float*)d_in[8];
  float* out = (float*)d_out;
  char* ws = (char*)d_ws;

  bf16* xcat = (bf16*)(ws + WS_XCAT);
  bf16* v2   = (bf16*)(ws + WS_V2);
  bf16* h2t  = (bf16*)(ws + WS_H2T);
  bf16* hT   = (bf16*)(ws + WS_HT);
  float* z   = (float*)(ws + WS_Z);
  bf16* w1b  = (bf16*)(ws + WS_W1B);
  bf16* w2b  = (bf16*)(ws + WS_W2B);
  bf16* w1ob = (bf16*)(ws + WS_W1OB);
  bf16* w2ob = (bf16*)(ws + WS_W2OB);
  float* nrmw = (float*)(ws + WS_NRM);
  float* sums = (float*)(ws + WS_SUMS);
  float* sc1 = (float*)(ws + WS_SC1);
  float* sh1 = (float*)(ws + WS_SH1);
  float* sc2 = (float*)(ws + WS_SC2);
  float* sh2 = (float*)(ws + WS_SH2);

  // weight casts + zero-init of accumulators and pad rows
  cast_k<<<16384, 256, 0, stream>>>(w1p, w1b, HIDN * CIN);
  cast_k<<<2048,  256, 0, stream>>>(w2p, w2b, OUTN * HIDN);
  cast_k<<<16384, 256, 0, stream>>>(w1o, w1ob, HIDN * CIN);
  cast_k<<<2048,  256, 0, stream>>>(w2o, w2ob, OUTN * HIDN);
  zero_f32<<<32, 256, 0, stream>>>(sums, 4 * 2048);
  zero_b16<<<512, 256, 0, stream>>>(xcat + (size_t)P1V * 2048, (P1P - P1V) * 2048);
  prep_k<<<2048, 256, 0, stream>>>(x, xcat);

  // MLP1: GEMM1 -> BN stats -> GEMM2(fused bn+relu)
  gemm_k<1><<<dim3(99, 16), 256, 0, stream>>>(xcat, w1b, hT, nullptr, nullptr);
  stats_k<<<dim3(8, 32), 256, 0, stream>>>(hT, P1V, 394, sums, sums + 2048);
  finalize_k<<<8, 256, 0, stream>>>(sums, sums + 2048, gp, bp, (float)P1V, sc1, sh1);
  gemm_k<2><<<dim3(4, 99), 256, 0, stream>>>(w2b, hT, z, sc1, sh1);

  // z_g, channel-norm, softmax (writes obj_attn twice)
  zg_k<<<64, 256, 0, stream>>>(z, out);
  nrm_k<<<64, 256, 0, stream>>>(z, nrmw);
  softmax_k<<<16384, 64, 0, stream>>>(z, nrmw, out);

  // attention-weighted values (einsum) -> MLP2
  gemm_k<5><<<512, 256, 0, stream>>>(out + O_ATT, x, v2, nullptr, nullptr);
  gemm_k<3><<<dim3(16, 16), 256, 0, stream>>>(v2, w1ob, h2t, nullptr, nullptr);
  stats_k<<<dim3(8, 8), 256, 0, stream>>>(h2t, 2048, 256, sums + 4096, sums + 6144);
  finalize_k<<<8, 256, 0, stream>>>(sums + 4096, sums + 6144, go, bo, 2048.f, sc2, sh2);
  gemm_k<4><<<dim3(4, 16), 256, 0, stream>>>(w2ob, h2t, out, sc2, sh2);
}